// Round 8
// baseline (935.466 us; speedup 1.0000x reference)
//
#include <hip/hip_runtime.h>

#define NPIX (512 * 512)
#define BLK 256

#define TOTB (NPIX * 6)
#define TOTS (NPIX * 3)
#define TOTE (NPIX * 9)

typedef unsigned long long u64;

constexpr float ALPHA_B = 32.0f / 33.0f;   // 1/(1+2^-5)
constexpr float ALPHA_S = 0.8f;            // 1/(1+2^-2)
constexpr float BI_COMPAT = 10.0f;
constexpr float SP_COMPAT = 3.0f;

// 4-byte CSR entry: [31:18] = weight (14-bit fixed point, /16383), [17:0] = pixel id
__device__ __forceinline__ unsigned pack_ent(int n, float w) {
    float wc = fminf(fmaxf(w, 0.f), 1.f);
    unsigned iw = (unsigned)(wc * 16383.f + 0.5f);
    return (iw << 18) | (unsigned)n;
}
__device__ __forceinline__ int ent_pix(unsigned e) { return (int)(e & 0x3FFFFu); }
__device__ __forceinline__ float ent_w(unsigned e) {
    return (float)(e >> 18) * (1.0f / 16383.0f);
}
// 8-byte list node: high 32 = next entry id (int, -1 sentinel), low 32 = packed ent
__device__ __forceinline__ u64 mknode(int nxt, unsigned pay) {
    return ((u64)(unsigned)nxt << 32) | (u64)pay;
}

__device__ __forceinline__ float4 f4zero() { return make_float4(0.f, 0.f, 0.f, 0.f); }

// ---------------- softmax init (fallback path) ----------------
__global__ void k_softmax_init(const float4* __restrict__ u, float4* __restrict__ Q) {
    int n = blockIdx.x * BLK + threadIdx.x;
    if (n >= NPIX) return;
    float4 uu = u[n];
    float l0 = -uu.x, l1 = -uu.y, l2 = -uu.z, l3 = -uu.w;
    float m = fmaxf(fmaxf(l0, l1), fmaxf(l2, l3));
    float e0 = expf(l0 - m), e1 = expf(l1 - m), e2 = expf(l2 - m), e3 = expf(l3 - m);
    float inv = 1.0f / (e0 + e1 + e2 + e3);
    Q[n] = make_float4(e0 * inv, e1 * inv, e2 * inv, e3 * inv);
}

// ---------------- linked-list build + softmax (8B payload nodes) ----------------
__global__ void k_link2_softmax(const int* __restrict__ osb, const float* __restrict__ wsb,
                                const int* __restrict__ oss, const float* __restrict__ wss,
                                int* __restrict__ head, u64* __restrict__ next2,
                                const float4* __restrict__ u, float4* __restrict__ Q,
                                int Vb) {
    int n = blockIdx.x * BLK + threadIdx.x;
    float4 uu = u[n];
    float l0 = -uu.x, l1 = -uu.y, l2 = -uu.z, l3 = -uu.w;
    float m = fmaxf(fmaxf(l0, l1), fmaxf(l2, l3));
    float e0 = expf(l0 - m), e1 = expf(l1 - m), e2 = expf(l2 - m), e3 = expf(l3 - m);
    float inv = 1.0f / (e0 + e1 + e2 + e3);
    Q[n] = make_float4(e0 * inv, e1 * inv, e2 * inv, e3 * inv);
#pragma unroll
    for (int r = 0; r < 6; r++) {
        int o = osb[n * 6 + r];
        int e = n * 6 + r;
        int old = atomicExch(&head[o], e);
        next2[e] = mknode(old, pack_ent(n, wsb[n * 6 + r]));
    }
#pragma unroll
    for (int r = 0; r < 3; r++) {
        int o = Vb + oss[n * 3 + r];
        int e = TOTB + n * 3 + r;
        int old = atomicExch(&head[o], e);
        next2[e] = mknode(old, pack_ent(n, wss[n * 3 + r]));
    }
}

// ---------------- CSR compaction, 8B nodes ----------------
__global__ void k_compact2(const int* __restrict__ head, const u64* __restrict__ next2,
                           unsigned* __restrict__ ent, int* __restrict__ start,
                           int* __restrict__ endv,
                           float* __restrict__ nB, float* __restrict__ nS,
                           int* __restrict__ cursor, int V, int Vb) {
    __shared__ int lds[BLK];
    __shared__ int sbase;
    int o = blockIdx.x * BLK + threadIdx.x;
    bool valid = o < V;
    int h = valid ? head[o] : -1;
    int len = 0;
    for (int e = h; e >= 0;) { e = (int)(next2[e] >> 32); len++; }
    lds[threadIdx.x] = len;
    __syncthreads();
    for (int off = 1; off < BLK; off <<= 1) {
        int t = ((int)threadIdx.x >= off) ? lds[threadIdx.x - off] : 0;
        __syncthreads();
        lds[threadIdx.x] += t;
        __syncthreads();
    }
    int incl = lds[threadIdx.x];
    if (threadIdx.x == BLK - 1) sbase = atomicAdd(cursor, incl);
    __syncthreads();
    if (!valid) return;
    int pos = sbase + incl - len;
    start[o] = pos;
    endv[o] = pos + len;
    float acc = 0.f;
    for (int e = h; e >= 0;) {
        u64 nd = next2[e];
        unsigned pe = (unsigned)nd;
        acc += ent_w(pe);
        ent[pos++] = pe;
        e = (int)(nd >> 32);
    }
    if (o < Vb) nB[o] = acc;
    else nS[o - Vb] = acc;
}

// ---------------- legacy 4B-node build (workspace-constrained fallback) ----------------
__global__ void k_link_softmax(const int* __restrict__ osb, const int* __restrict__ oss,
                               int* __restrict__ head, int* __restrict__ next,
                               const float4* __restrict__ u, float4* __restrict__ Q,
                               int Vb) {
    int n = blockIdx.x * BLK + threadIdx.x;
    if (n >= NPIX) return;
    float4 uu = u[n];
    float l0 = -uu.x, l1 = -uu.y, l2 = -uu.z, l3 = -uu.w;
    float m = fmaxf(fmaxf(l0, l1), fmaxf(l2, l3));
    float e0 = expf(l0 - m), e1 = expf(l1 - m), e2 = expf(l2 - m), e3 = expf(l3 - m);
    float inv = 1.0f / (e0 + e1 + e2 + e3);
    Q[n] = make_float4(e0 * inv, e1 * inv, e2 * inv, e3 * inv);
#pragma unroll
    for (int r = 0; r < 6; r++) {
        int o = osb[n * 6 + r];
        int e = n * 6 + r;
        next[e] = atomicExch(&head[o], e);
    }
#pragma unroll
    for (int r = 0; r < 3; r++) {
        int o = Vb + oss[n * 3 + r];
        int e = TOTB + n * 3 + r;
        next[e] = atomicExch(&head[o], e);
    }
}

__global__ void k_compact(const int* __restrict__ head, const int* __restrict__ next,
                          const float* __restrict__ wsb, const float* __restrict__ wss,
                          unsigned* __restrict__ ent, int* __restrict__ start,
                          int* __restrict__ endv,
                          float* __restrict__ nB, float* __restrict__ nS,
                          int* __restrict__ cursor, int V, int Vb) {
    __shared__ int lds[BLK];
    __shared__ int sbase;
    int o = blockIdx.x * BLK + threadIdx.x;
    bool valid = o < V;
    int h = valid ? head[o] : -1;
    int len = 0;
    for (int e = h; e >= 0; e = next[e]) len++;
    lds[threadIdx.x] = len;
    __syncthreads();
    for (int off = 1; off < BLK; off <<= 1) {
        int t = ((int)threadIdx.x >= off) ? lds[threadIdx.x - off] : 0;
        __syncthreads();
        lds[threadIdx.x] += t;
        __syncthreads();
    }
    int incl = lds[threadIdx.x];
    if (threadIdx.x == BLK - 1) sbase = atomicAdd(cursor, incl);
    __syncthreads();
    if (!valid) return;
    int pos = sbase + incl - len;
    start[o] = pos;
    endv[o] = pos + len;
    float acc = 0.f;
    if (o < Vb) {
        for (int e = h; e >= 0; e = next[e]) {
            unsigned n = (unsigned)e / 6u;
            unsigned pe = pack_ent((int)n, wsb[e]);
            acc += ent_w(pe);
            ent[pos++] = pe;
        }
        nB[o] = acc;
    } else {
        for (int e = h; e >= 0; e = next[e]) {
            int ee = e - TOTB;
            unsigned pe = pack_ent(ee / 3, wss[ee]);
            acc += ent_w(pe);
            ent[pos++] = pe;
        }
        nS[o - Vb] = acc;
    }
}

// ---------------- composed 2-hop blur index build ----------------
// out = Bk(Bj in):  out[i] = in[i] + .5(in[a1]+in[a2]+in[A]+in[B])
//                          + .25(in[A1]+in[A2]+in[B1]+in[B2])
// A,B = bn_k[i]; a* = bn_j[i]; A* = bn_j[A]; B* = bn_j[B]; missing -> 0 and
// in[0]==0 keeps the algebra exact. Planes (stride V): a1 a2 A A1 A2 B B1 B2.
__global__ void k_compose(const int* __restrict__ bnb, int Mb, int Vb,
                          const int* __restrict__ bns, int Ms, int Vs,
                          int* __restrict__ cidxB, int* __restrict__ cidxS) {
    int t = blockIdx.x * BLK + threadIdx.x;
    int TB = 3 * Vb;
    const int* bnj; const int* bnk; int* c; int i, V;
    if (t < TB) {
        int p = t / Vb;
        i = t - p * Vb;
        if (i == 0) return;
        bnj = bnb + (size_t)(2 * p) * Mb * 2;
        bnk = bnb + (size_t)(2 * p + 1) * Mb * 2;
        c = cidxB + (size_t)p * 8 * Vb;
        V = Vb;
    } else {
        i = t - TB;
        if (i >= Vs || i == 0) return;
        bnj = bns;
        bnk = bns + (size_t)Ms * 2;
        c = cidxS;
        V = Vs;
    }
    int A = bnk[(size_t)(i - 1) * 2 + 0];
    int B = bnk[(size_t)(i - 1) * 2 + 1];
    int a1 = bnj[(size_t)(i - 1) * 2 + 0];
    int a2 = bnj[(size_t)(i - 1) * 2 + 1];
    int A1 = 0, A2 = 0, B1 = 0, B2 = 0;
    if (A > 0) { A1 = bnj[(size_t)(A - 1) * 2 + 0]; A2 = bnj[(size_t)(A - 1) * 2 + 1]; }
    if (B > 0) { B1 = bnj[(size_t)(B - 1) * 2 + 0]; B2 = bnj[(size_t)(B - 1) * 2 + 1]; }
    c[0 * (size_t)V + i] = a1;
    c[1 * (size_t)V + i] = a2;
    c[2 * (size_t)V + i] = A;
    c[3 * (size_t)V + i] = A1;
    c[4 * (size_t)V + i] = A2;
    c[5 * (size_t)V + i] = B;
    c[6 * (size_t)V + i] = B1;
    c[7 * (size_t)V + i] = B2;
}

// ---------------- fused 2-hop blur cores (fp32 tables) ----------------
__device__ __forceinline__ void blur2f4_core(const float4* __restrict__ in, float4* __restrict__ out,
                                             const int* __restrict__ c, int V, int i) {
    if (i == 0) { out[0] = f4zero(); return; }
    int a1 = c[0 * (size_t)V + i], a2 = c[1 * (size_t)V + i];
    int A  = c[2 * (size_t)V + i], A1 = c[3 * (size_t)V + i], A2 = c[4 * (size_t)V + i];
    int B  = c[5 * (size_t)V + i], B1 = c[6 * (size_t)V + i], B2 = c[7 * (size_t)V + i];
    float4 vi = in[i], va1 = in[a1], va2 = in[a2];
    float4 vA = in[A], vA1 = in[A1], vA2 = in[A2];
    float4 vB = in[B], vB1 = in[B1], vB2 = in[B2];
    float4 o;
    o.x = vi.x + 0.5f * (va1.x + va2.x + vA.x + vB.x) + 0.25f * (vA1.x + vA2.x + vB1.x + vB2.x);
    o.y = vi.y + 0.5f * (va1.y + va2.y + vA.y + vB.y) + 0.25f * (vA1.y + vA2.y + vB1.y + vB2.y);
    o.z = vi.z + 0.5f * (va1.z + va2.z + vA.z + vB.z) + 0.25f * (vA1.z + vA2.z + vB1.z + vB2.z);
    o.w = vi.w + 0.5f * (va1.w + va2.w + vA.w + vB.w) + 0.25f * (vA1.w + vA2.w + vB1.w + vB2.w);
    out[i] = o;
}

__device__ __forceinline__ void blur2f_core(const float* __restrict__ in, float* __restrict__ out,
                                            const int* __restrict__ c, int V, int i) {
    if (i == 0) { out[0] = 0.f; return; }
    int a1 = c[0 * (size_t)V + i], a2 = c[1 * (size_t)V + i];
    int A  = c[2 * (size_t)V + i], A1 = c[3 * (size_t)V + i], A2 = c[4 * (size_t)V + i];
    int B  = c[5 * (size_t)V + i], B1 = c[6 * (size_t)V + i], B2 = c[7 * (size_t)V + i];
    out[i] = in[i] + 0.5f * (in[a1] + in[a2] + in[A] + in[B])
                   + 0.25f * (in[A1] + in[A2] + in[B1] + in[B2]);
}

__device__ __forceinline__ void blur1f4_core(const float4* __restrict__ in, float4* __restrict__ out,
                                             const int* __restrict__ bn, int i) {
    if (i == 0) { out[0] = f4zero(); return; }
    int n1 = bn[(size_t)(i - 1) * 2 + 0];
    int n2 = bn[(size_t)(i - 1) * 2 + 1];
    float4 a = in[i], b = in[n1], c = in[n2];
    out[i] = make_float4(a.x + 0.5f * (b.x + c.x), a.y + 0.5f * (b.y + c.y),
                         a.z + 0.5f * (b.z + c.z), a.w + 0.5f * (b.w + c.w));
}

// fused-pair on both lattices (float4)
__global__ void k_blur2f4_both(const float4* __restrict__ inB, float4* __restrict__ outB,
                               const int* __restrict__ cB, int Vb,
                               const float4* __restrict__ inS, float4* __restrict__ outS,
                               const int* __restrict__ cS, int Vs) {
    int i = blockIdx.x * BLK + threadIdx.x;
    if (i < Vb) blur2f4_core(inB, outB, cB, Vb, i);
    else if (i - Vb < Vs) blur2f4_core(inS, outS, cS, Vs, i - Vb);
}
// fused-pair bilateral + single-hop spatial (float4)
__global__ void k_blur2f4_b1s(const float4* __restrict__ inB, float4* __restrict__ outB,
                              const int* __restrict__ cB, int Vb,
                              const float4* __restrict__ inS, float4* __restrict__ outS,
                              const int* __restrict__ bnS, int Vs) {
    int i = blockIdx.x * BLK + threadIdx.x;
    if (i < Vb) blur2f4_core(inB, outB, cB, Vb, i);
    else if (i - Vb < Vs) blur1f4_core(inS, outS, bnS, i - Vb);
}
// fused-pair bilateral only (float4)
__global__ void k_blur2f4_b(const float4* __restrict__ inB, float4* __restrict__ outB,
                            const int* __restrict__ cB, int Vb) {
    int i = blockIdx.x * BLK + threadIdx.x;
    if (i < Vb) blur2f4_core(inB, outB, cB, Vb, i);
}
// fp32 scalar variants for the normalizer chain
__global__ void k_blur2f_both(const float* __restrict__ inB, float* __restrict__ outB,
                              const int* __restrict__ cB, int Vb,
                              const float* __restrict__ inS, float* __restrict__ outS,
                              const int* __restrict__ cS, int Vs) {
    int i = blockIdx.x * BLK + threadIdx.x;
    if (i < Vb) blur2f_core(inB, outB, cB, Vb, i);
    else if (i - Vb < Vs) blur2f_core(inS, outS, cS, Vs, i - Vb);
}
__global__ void k_blur2f_b1s(const float* __restrict__ inB, float* __restrict__ outB,
                             const int* __restrict__ cB, int Vb,
                             const float* __restrict__ inS, float* __restrict__ outS,
                             const int* __restrict__ bnS, int Vs) {
    int i = blockIdx.x * BLK + threadIdx.x;
    if (i < Vb) blur2f_core(inB, outB, cB, Vb, i);
    else if (i - Vb < Vs) {
        int idx = i - Vb;
        if (idx == 0) { outS[0] = 0.f; return; }
        int n1 = bnS[(size_t)(idx - 1) * 2 + 0];
        int n2 = bnS[(size_t)(idx - 1) * 2 + 1];
        outS[idx] = inS[idx] + 0.5f * (inS[n1] + inS[n2]);
    }
}
__global__ void k_blur2f_b(const float* __restrict__ inB, float* __restrict__ outB,
                           const int* __restrict__ cB, int Vb) {
    int i = blockIdx.x * BLK + threadIdx.x;
    if (i < Vb) blur2f_core(inB, outB, cB, Vb, i);
}

// ---------------- gather-based splat (fp32 tables) ----------------
__global__ void k_gather4f_both(const unsigned* __restrict__ ent, const int* __restrict__ start,
                                const int* __restrict__ endv, int V, int Vb,
                                float4* __restrict__ tB, float4* __restrict__ tS,
                                const float4* __restrict__ Q) {
    int i = blockIdx.x * BLK + threadIdx.x;
    if (i >= V) return;
    int s = start[i];
    int e = endv[i];
    float ax = 0.f, ay = 0.f, az = 0.f, aw = 0.f;
    for (int k = s; k < e; k++) {
        unsigned en = ent[k];
        float w = ent_w(en);
        float4 q = Q[ent_pix(en)];
        ax += w * q.x; ay += w * q.y; az += w * q.z; aw += w * q.w;
    }
    float4 h = make_float4(ax, ay, az, aw);
    if (i < Vb) tB[i] = h;
    else tS[i - Vb] = h;
}

// ---------------- plain 1-hop blurs (unfused tier + fallback) ----------------
__global__ void k_blur1(const float* __restrict__ in, float* __restrict__ out,
                        const int* __restrict__ bn, int M) {
    int i = blockIdx.x * BLK + threadIdx.x;
    if (i > M) return;
    if (i == 0) { out[0] = 0.f; return; }
    int n1 = bn[(size_t)(i - 1) * 2 + 0];
    int n2 = bn[(size_t)(i - 1) * 2 + 1];
    out[i] = in[i] + 0.5f * (in[n1] + in[n2]);
}

__global__ void k_blur1_both(const float* __restrict__ inB, float* __restrict__ outB,
                             const int* __restrict__ bnB, int Mb,
                             const float* __restrict__ inS, float* __restrict__ outS,
                             const int* __restrict__ bnS, int Ms) {
    int i = blockIdx.x * BLK + threadIdx.x;
    const float* in; float* out; const int* bn; int M, idx;
    if (i <= Mb) { in = inB; out = outB; bn = bnB; M = Mb; idx = i; }
    else {
        idx = i - (Mb + 1);
        if (idx > Ms) return;
        in = inS; out = outS; bn = bnS; M = Ms;
    }
    if (idx == 0) { out[0] = 0.f; return; }
    int n1 = bn[(size_t)(idx - 1) * 2 + 0];
    int n2 = bn[(size_t)(idx - 1) * 2 + 1];
    out[idx] = in[idx] + 0.5f * (in[n1] + in[n2]);
}

__global__ void k_blur4(const float4* __restrict__ in, float4* __restrict__ out,
                        const int* __restrict__ bn, int M) {
    int i = blockIdx.x * BLK + threadIdx.x;
    if (i > M) return;
    blur1f4_core(in, out, bn, i);
}

__global__ void k_blur4_both(const float4* __restrict__ inB, float4* __restrict__ outB,
                             const int* __restrict__ bnB, int Mb,
                             const float4* __restrict__ inS, float4* __restrict__ outS,
                             const int* __restrict__ bnS, int Ms) {
    int i = blockIdx.x * BLK + threadIdx.x;
    if (i <= Mb) blur1f4_core(inB, outB, bnB, i);
    else if (i - (Mb + 1) <= Ms) blur1f4_core(inS, outS, bnS, i - (Mb + 1));
}

// ---------------- normalizer slice + weight prescale ----------------
__global__ void k_norm_prescale(const float* __restrict__ nTb, const float* __restrict__ wsb,
                                const int* __restrict__ osb,
                                const float* __restrict__ nTs, const float* __restrict__ wss,
                                const int* __restrict__ oss,
                                float* __restrict__ wsbp, float* __restrict__ wssp) {
    int n = blockIdx.x * BLK + threadIdx.x;
    if (n >= NPIX) return;
    float sb = 0.f;
#pragma unroll
    for (int r = 0; r < 6; r++) sb += wsb[n * 6 + r] * nTb[osb[n * 6 + r]];
    float cb = BI_COMPAT * ALPHA_B / (ALPHA_B * sb + 1e-20f);
#pragma unroll
    for (int r = 0; r < 6; r++) wsbp[n * 6 + r] = wsb[n * 6 + r] * cb;
    float ss = 0.f;
#pragma unroll
    for (int r = 0; r < 3; r++) ss += wss[n * 3 + r] * nTs[oss[n * 3 + r]];
    float cs = SP_COMPAT * ALPHA_S / (ALPHA_S * ss + 1e-20f);
#pragma unroll
    for (int r = 0; r < 3; r++) wssp[n * 3 + r] = wss[n * 3 + r] * cs;
}

// ---------------- fused slice + message + softmax (fp32 tables) ----------------
__global__ void k_slice_combine_f(const float4* __restrict__ u,
                                  const float4* __restrict__ tb, const float* __restrict__ wsbp,
                                  const int* __restrict__ osb,
                                  const float4* __restrict__ ts, const float* __restrict__ wssp,
                                  const int* __restrict__ oss,
                                  float4* __restrict__ Qout) {
    int n = blockIdx.x * BLK + threadIdx.x;
    if (n >= NPIX) return;
    float4 uu = u[n];
    float l0 = -uu.x, l1 = -uu.y, l2 = -uu.z, l3 = -uu.w;
#pragma unroll
    for (int r = 0; r < 6; r++) {
        float w = wsbp[n * 6 + r];
        float4 t = tb[osb[n * 6 + r]];
        l0 += w * t.x; l1 += w * t.y; l2 += w * t.z; l3 += w * t.w;
    }
#pragma unroll
    for (int r = 0; r < 3; r++) {
        float w = wssp[n * 3 + r];
        float4 t = ts[oss[n * 3 + r]];
        l0 += w * t.x; l1 += w * t.y; l2 += w * t.z; l3 += w * t.w;
    }
    float m = fmaxf(fmaxf(l0, l1), fmaxf(l2, l3));
    float e0 = expf(l0 - m), e1 = expf(l1 - m), e2 = expf(l2 - m), e3 = expf(l3 - m);
    float inv = 1.0f / (e0 + e1 + e2 + e3);
    Qout[n] = make_float4(e0 * inv, e1 * inv, e2 * inv, e3 * inv);
}

// ---------------- fallback (fp32 atomic splat path) ----------------
template <int D1>
__global__ void k_splat1(const float* __restrict__ ws, const int* __restrict__ os,
                         float* __restrict__ table) {
    int n = blockIdx.x * BLK + threadIdx.x;
    if (n >= NPIX) return;
#pragma unroll
    for (int r = 0; r < D1; r++) atomicAdd(&table[os[n * D1 + r]], ws[n * D1 + r]);
}

template <int D1>
__global__ void k_splat4(const float4* __restrict__ Q, const float* __restrict__ ws,
                         const int* __restrict__ os, float* __restrict__ table) {
    int n = blockIdx.x * BLK + threadIdx.x;
    if (n >= NPIX) return;
    float4 q = Q[n];
#pragma unroll
    for (int r = 0; r < D1; r++) {
        float w = ws[n * D1 + r];
        int o = os[n * D1 + r];
        float* t = table + 4 * (size_t)o;
        atomicAdd(t + 0, q.x * w);
        atomicAdd(t + 1, q.y * w);
        atomicAdd(t + 2, q.z * w);
        atomicAdd(t + 3, q.w * w);
    }
}

template <int D1>
__global__ void k_norm_slice(const float* __restrict__ table, const float* __restrict__ ws,
                             const int* __restrict__ os, float alpha,
                             float* __restrict__ inv_out) {
    int n = blockIdx.x * BLK + threadIdx.x;
    if (n >= NPIX) return;
    float s = 0.f;
#pragma unroll
    for (int r = 0; r < D1; r++) s += ws[n * D1 + r] * table[os[n * D1 + r]];
    inv_out[n] = 1.0f / (alpha * s + 1e-20f);
}

__global__ void k_slice_combine(const float4* __restrict__ u,
                                const float4* __restrict__ tb, const float* __restrict__ wsb,
                                const int* __restrict__ osb,
                                const float4* __restrict__ ts, const float* __restrict__ wss,
                                const int* __restrict__ oss,
                                const float* __restrict__ inv_nb,
                                const float* __restrict__ inv_ns,
                                float4* __restrict__ Qout) {
    int n = blockIdx.x * BLK + threadIdx.x;
    if (n >= NPIX) return;
    float4 ab = f4zero();
#pragma unroll
    for (int r = 0; r < 6; r++) {
        float w = wsb[n * 6 + r];
        float4 t = tb[osb[n * 6 + r]];
        ab.x += w * t.x; ab.y += w * t.y; ab.z += w * t.z; ab.w += w * t.w;
    }
    float4 as = f4zero();
#pragma unroll
    for (int r = 0; r < 3; r++) {
        float w = wss[n * 3 + r];
        float4 t = ts[oss[n * 3 + r]];
        as.x += w * t.x; as.y += w * t.y; as.z += w * t.z; as.w += w * t.w;
    }
    float cb = BI_COMPAT * ALPHA_B * inv_nb[n];
    float cs = SP_COMPAT * ALPHA_S * inv_ns[n];
    float4 uu = u[n];
    float l0 = -uu.x + cb * ab.x + cs * as.x;
    float l1 = -uu.y + cb * ab.y + cs * as.y;
    float l2 = -uu.z + cb * ab.z + cs * as.z;
    float l3 = -uu.w + cb * ab.w + cs * as.w;
    float m = fmaxf(fmaxf(l0, l1), fmaxf(l2, l3));
    float e0 = expf(l0 - m), e1 = expf(l1 - m), e2 = expf(l2 - m), e3 = expf(l3 - m);
    float inv = 1.0f / (e0 + e1 + e2 + e3);
    Qout[n] = make_float4(e0 * inv, e1 * inv, e2 * inv, e3 * inv);
}

extern "C" void kernel_launch(void* const* d_in, const int* in_sizes, int n_in,
                              void* d_out, int out_size, void* d_ws, size_t ws_size,
                              hipStream_t stream) {
    const float* unary = (const float*)d_in[0];
    const float* wsb   = (const float*)d_in[1];
    const int*   osb   = (const int*)d_in[2];
    const int*   bnb   = (const int*)d_in[3];
    const float* wss   = (const float*)d_in[5];
    const int*   oss   = (const int*)d_in[6];
    const int*   bns   = (const int*)d_in[7];
    const int Mb = in_sizes[3] / 12;   // bn_b is (6, Mb, 2)
    const int Ms = in_sizes[7] / 6;    // bn_s is (3, Ms, 2)
    const int Vb = Mb + 1, Vs = Ms + 1;
    const int V = Vb + Vs;

    float* Q = (float*)d_out;  // N x 4, final value IS the output

    char* p = (char*)d_ws;
    auto alloc = [&](size_t nbytes) -> void* {
        void* r = (void*)p;
        p += (nbytes + 15) & ~(size_t)15;
        return r;
    };
    // ---- aliasable region (4B-fallback only): first WRITTEN after k_compact ----
    // wsbp+wssp = TOTE*4 bytes exactly -> next4 always fits here.
    char* region0 = p;
    float* wsbp = (float*)alloc((size_t)NPIX * 6 * 4);
    float* wssp = (float*)alloc((size_t)NPIX * 3 * 4);
    float4* tAb = (float4*)alloc((size_t)Vb * 16);
    float4* tBb = (float4*)alloc((size_t)Vb * 16);
    float4* tAs = (float4*)alloc((size_t)Vs * 16);
    float4* tBs = (float4*)alloc((size_t)Vs * 16);
    float* nBb = (float*)alloc((size_t)Vb * 4);
    float* nBs = (float*)alloc((size_t)Vs * 4);
    // ---- non-aliased (live across build) ----
    float* nAb = (float*)alloc((size_t)Vb * 4);
    float* nAs = (float*)alloc((size_t)Vs * 4);
    int*  start = (int*)alloc((size_t)V * 4);
    int*  endv  = (int*)alloc((size_t)V * 4);
    int*  head  = (int*)alloc((size_t)V * 4);
    unsigned* ent = (unsigned*)alloc((size_t)TOTE * 4);
    int*  cursor = (int*)alloc(16);
    size_t base_need = (size_t)(p - (char*)d_ws);
    u64*  next2 = (u64*)alloc((size_t)TOTE * 8);        // dedicated tail
    size_t need8 = (size_t)(p - (char*)d_ws);
    // composed 2-hop indices: bilateral 3 pairs x 8 planes x Vb, spatial 1 x 8 x Vs
    int* cidxB = (int*)alloc((size_t)Vb * 8 * 3 * 4);
    int* cidxS = (int*)alloc((size_t)Vs * 8 * 4);
    size_t need_fused = (size_t)(p - (char*)d_ws);
    bool use_gather = base_need <= ws_size;
    bool use8 = need8 <= ws_size;
    bool use_fused = need_fused <= ws_size;
    int*  next4 = (int*)region0;

    dim3 blk(BLK);
    dim3 gN((NPIX + BLK - 1) / BLK);
    dim3 gVb((Vb + BLK - 1) / BLK);
    dim3 gV((V + BLK - 1) / BLK);
    dim3 gVBS((Vb + Vs + BLK - 1) / BLK);
    dim3 gC((3 * Vb + Vs + BLK - 1) / BLK);

    if (use_gather) {
        // ---- build CSR via linked-list inversion + compaction ----
        hipMemsetAsync(head, 0xFF, (size_t)V * 4, stream);  // -1 sentinel
        hipMemsetAsync(cursor, 0, 16, stream);
        if (use_fused)
            k_compose<<<gC, blk, 0, stream>>>(bnb, Mb, Vb, bns, Ms, Vs, cidxB, cidxS);
        if (use8) {
            k_link2_softmax<<<gN, blk, 0, stream>>>(osb, wsb, oss, wss, head, next2,
                                                    (const float4*)unary, (float4*)Q, Vb);
            k_compact2<<<gV, blk, 0, stream>>>(head, next2, ent, start, endv,
                                               nAb, nAs, cursor, V, Vb);
        } else {
            k_link_softmax<<<gN, blk, 0, stream>>>(osb, oss, head, next4,
                                                   (const float4*)unary, (float4*)Q, Vb);
            k_compact<<<gV, blk, 0, stream>>>(head, next4, wsb, wss, ent, start, endv,
                                              nAb, nAs, cursor, V, Vb);
        }

        const int* cB01 = cidxB;
        const int* cB23 = cidxB + (size_t)1 * 8 * Vb;
        const int* cB45 = cidxB + (size_t)2 * 8 * Vb;
        const int* bnS2 = bns + (size_t)2 * Ms * 2;

        // ---- normalizer chain + prescale ----
        if (use_fused) {
            k_blur2f_both<<<gVBS, blk, 0, stream>>>(nAb, nBb, cB01, Vb, nAs, nBs, cidxS, Vs);
            k_blur2f_b1s<<<gVBS, blk, 0, stream>>>(nBb, nAb, cB23, Vb, nBs, nAs, bnS2, Vs);
            k_blur2f_b<<<gVb, blk, 0, stream>>>(nAb, nBb, cB45, Vb);
            k_norm_prescale<<<gN, blk, 0, stream>>>(nBb, wsb, osb, nAs, wss, oss, wsbp, wssp);
        } else {
            float* a = nAb; float* b = nBb;
            float* as_ = nAs; float* bs_ = nBs;
            for (int j = 0; j < 3; j++) {
                k_blur1_both<<<gVBS, blk, 0, stream>>>(a, b, bnb + (size_t)j * Mb * 2, Mb,
                                                       as_, bs_, bns + (size_t)j * Ms * 2, Ms);
                float* t = a; a = b; b = t;
                t = as_; as_ = bs_; bs_ = t;
            }
            for (int j = 3; j < 6; j++) {
                k_blur1<<<gVb, blk, 0, stream>>>(a, b, bnb + (size_t)j * Mb * 2, Mb);
                float* t = a; a = b; b = t;
            }
            k_norm_prescale<<<gN, blk, 0, stream>>>(a, wsb, osb, as_, wss, oss, wsbp, wssp);
        }

        // ---- 10 mean-field iterations ----
        for (int it = 0; it < 10; it++) {
            k_gather4f_both<<<gV, blk, 0, stream>>>(ent, start, endv, V, Vb, tAb, tAs,
                                                    (const float4*)Q);
            if (use_fused) {
                // bil: tAb -(01)-> tBb -(23)-> tAb -(45)-> tBb ; sp: tAs -(01)-> tBs -(2)-> tAs
                k_blur2f4_both<<<gVBS, blk, 0, stream>>>(tAb, tBb, cB01, Vb, tAs, tBs, cidxS, Vs);
                k_blur2f4_b1s<<<gVBS, blk, 0, stream>>>(tBb, tAb, cB23, Vb, tBs, tAs, bnS2, Vs);
                k_blur2f4_b<<<gVb, blk, 0, stream>>>(tAb, tBb, cB45, Vb);
                k_slice_combine_f<<<gN, blk, 0, stream>>>((const float4*)unary,
                                                          tBb, wsbp, osb, tAs, wssp, oss,
                                                          (float4*)Q);
            } else {
                float4* a = tAb; float4* b = tBb;
                float4* as_ = tAs; float4* bs_ = tBs;
                for (int j = 0; j < 3; j++) {
                    k_blur4_both<<<gVBS, blk, 0, stream>>>(a, b, bnb + (size_t)j * Mb * 2, Mb,
                                                           as_, bs_, bns + (size_t)j * Ms * 2, Ms);
                    float4* t = a; a = b; b = t;
                    t = as_; as_ = bs_; bs_ = t;
                }
                for (int j = 3; j < 6; j++) {
                    k_blur4<<<gVb, blk, 0, stream>>>(a, b, bnb + (size_t)j * Mb * 2, Mb);
                    float4* t = a; a = b; b = t;
                }
                k_slice_combine_f<<<gN, blk, 0, stream>>>((const float4*)unary,
                                                          a, wsbp, osb, as_, wssp, oss,
                                                          (float4*)Q);
            }
        }
    } else {
        // ---- fallback: fp32 atomic splat path ----
        char* q = (char*)d_ws;
        auto alloc2 = [&](size_t nbytes) -> void* {
            void* r = (void*)q;
            q += (nbytes + 15) & ~(size_t)15;
            return r;
        };
        float* fAb = (float*)alloc2((size_t)Vb * 4 * sizeof(float));
        float* fBb = (float*)alloc2((size_t)Vb * 4 * sizeof(float));
        float* fAs = (float*)alloc2((size_t)Vs * 4 * sizeof(float));
        float* fBs = (float*)alloc2((size_t)Vs * 4 * sizeof(float));
        float* inv_nb = (float*)alloc2(NPIX * sizeof(float));
        float* inv_ns = (float*)alloc2(NPIX * sizeof(float));
        dim3 gMb((Mb + 1 + BLK - 1) / BLK);
        dim3 gMs((Ms + 1 + BLK - 1) / BLK);

        hipMemsetAsync(fAb, 0, (size_t)Vb * sizeof(float), stream);
        k_splat1<6><<<gN, blk, 0, stream>>>(wsb, osb, fAb);
        {
            float* a = fAb; float* b = fBb;
            for (int j = 0; j < 6; j++) {
                k_blur1<<<gMb, blk, 0, stream>>>(a, b, bnb + (size_t)j * Mb * 2, Mb);
                float* t = a; a = b; b = t;
            }
            k_norm_slice<6><<<gN, blk, 0, stream>>>(a, wsb, osb, ALPHA_B, inv_nb);
        }
        hipMemsetAsync(fAs, 0, (size_t)Vs * sizeof(float), stream);
        k_splat1<3><<<gN, blk, 0, stream>>>(wss, oss, fAs);
        {
            float* a = fAs; float* b = fBs;
            for (int j = 0; j < 3; j++) {
                k_blur1<<<gMs, blk, 0, stream>>>(a, b, bns + (size_t)j * Ms * 2, Ms);
                float* t = a; a = b; b = t;
            }
            k_norm_slice<3><<<gN, blk, 0, stream>>>(a, wss, oss, ALPHA_S, inv_ns);
        }
        k_softmax_init<<<gN, blk, 0, stream>>>((const float4*)unary, (float4*)Q);
        for (int it = 0; it < 10; it++) {
            hipMemsetAsync(fAb, 0, (size_t)Vb * 4 * sizeof(float), stream);
            k_splat4<6><<<gN, blk, 0, stream>>>((const float4*)Q, wsb, osb, fAb);
            float* a = fAb; float* b = fBb;
            for (int j = 0; j < 6; j++) {
                k_blur4<<<gMb, blk, 0, stream>>>((const float4*)a, (float4*)b,
                                                 bnb + (size_t)j * Mb * 2, Mb);
                float* t = a; a = b; b = t;
            }
            float* finb = a;
            hipMemsetAsync(fAs, 0, (size_t)Vs * 4 * sizeof(float), stream);
            k_splat4<3><<<gN, blk, 0, stream>>>((const float4*)Q, wss, oss, fAs);
            float* as_ = fAs; float* bs_ = fBs;
            for (int j = 0; j < 3; j++) {
                k_blur4<<<gMs, blk, 0, stream>>>((const float4*)as_, (float4*)bs_,
                                                 bns + (size_t)j * Ms * 2, Ms);
                float* t = as_; as_ = bs_; bs_ = t;
            }
            float* fins = as_;
            k_slice_combine<<<gN, blk, 0, stream>>>((const float4*)unary,
                                                    (const float4*)finb, wsb, osb,
                                                    (const float4*)fins, wss, oss,
                                                    inv_nb, inv_ns, (float4*)Q);
        }
    }
}

// Round 9
// 869.795 us; speedup vs baseline: 1.0755x; 1.0755x over previous
//
#include <hip/hip_runtime.h>

#define NPIX (512 * 512)
#define BLK 256

#define TOTB (NPIX * 6)
#define TOTS (NPIX * 3)
#define TOTE (NPIX * 9)

typedef unsigned long long u64;

constexpr float ALPHA_B = 32.0f / 33.0f;   // 1/(1+2^-5)
constexpr float ALPHA_S = 0.8f;            // 1/(1+2^-2)
constexpr float BI_COMPAT = 10.0f;
constexpr float SP_COMPAT = 3.0f;

// 4-byte CSR entry: [31:18] = weight (14-bit fixed point, /16383), [17:0] = pixel id
__device__ __forceinline__ unsigned pack_ent(int n, float w) {
    float wc = fminf(fmaxf(w, 0.f), 1.f);
    unsigned iw = (unsigned)(wc * 16383.f + 0.5f);
    return (iw << 18) | (unsigned)n;
}
__device__ __forceinline__ int ent_pix(unsigned e) { return (int)(e & 0x3FFFFu); }
__device__ __forceinline__ float ent_w(unsigned e) {
    return (float)(e >> 18) * (1.0f / 16383.0f);
}
// 8-byte list node: high 32 = next entry id (int, -1 sentinel), low 32 = packed ent
__device__ __forceinline__ u64 mknode(int nxt, unsigned pay) {
    return ((u64)(unsigned)nxt << 32) | (u64)pay;
}

__device__ __forceinline__ float4 f4zero() { return make_float4(0.f, 0.f, 0.f, 0.f); }

// ---------------- softmax init (fallback path) ----------------
__global__ void k_softmax_init(const float4* __restrict__ u, float4* __restrict__ Q) {
    int n = blockIdx.x * BLK + threadIdx.x;
    if (n >= NPIX) return;
    float4 uu = u[n];
    float l0 = -uu.x, l1 = -uu.y, l2 = -uu.z, l3 = -uu.w;
    float m = fmaxf(fmaxf(l0, l1), fmaxf(l2, l3));
    float e0 = expf(l0 - m), e1 = expf(l1 - m), e2 = expf(l2 - m), e3 = expf(l3 - m);
    float inv = 1.0f / (e0 + e1 + e2 + e3);
    Q[n] = make_float4(e0 * inv, e1 * inv, e2 * inv, e3 * inv);
}

// ---------------- linked-list build + softmax (8B payload nodes) ----------------
__global__ void k_link2_softmax(const int* __restrict__ osb, const float* __restrict__ wsb,
                                const int* __restrict__ oss, const float* __restrict__ wss,
                                int* __restrict__ head, u64* __restrict__ next2,
                                const float4* __restrict__ u, float4* __restrict__ Q,
                                int Vb) {
    int n = blockIdx.x * BLK + threadIdx.x;
    float4 uu = u[n];
    float l0 = -uu.x, l1 = -uu.y, l2 = -uu.z, l3 = -uu.w;
    float m = fmaxf(fmaxf(l0, l1), fmaxf(l2, l3));
    float e0 = expf(l0 - m), e1 = expf(l1 - m), e2 = expf(l2 - m), e3 = expf(l3 - m);
    float inv = 1.0f / (e0 + e1 + e2 + e3);
    Q[n] = make_float4(e0 * inv, e1 * inv, e2 * inv, e3 * inv);
#pragma unroll
    for (int r = 0; r < 6; r++) {
        int o = osb[n * 6 + r];
        int e = n * 6 + r;
        int old = atomicExch(&head[o], e);
        next2[e] = mknode(old, pack_ent(n, wsb[n * 6 + r]));
    }
#pragma unroll
    for (int r = 0; r < 3; r++) {
        int o = Vb + oss[n * 3 + r];
        int e = TOTB + n * 3 + r;
        int old = atomicExch(&head[o], e);
        next2[e] = mknode(old, pack_ent(n, wss[n * 3 + r]));
    }
}

// ---------------- CSR compaction, 8B nodes; writes packed (start,end) ----------------
__global__ void k_compact2(const int* __restrict__ head, const u64* __restrict__ next2,
                           unsigned* __restrict__ ent, int2* __restrict__ se,
                           float* __restrict__ nB, float* __restrict__ nS,
                           int* __restrict__ cursor, int V, int Vb) {
    __shared__ int lds[BLK];
    __shared__ int sbase;
    int o = blockIdx.x * BLK + threadIdx.x;
    bool valid = o < V;
    int h = valid ? head[o] : -1;
    int len = 0;
    for (int e = h; e >= 0;) { e = (int)(next2[e] >> 32); len++; }
    lds[threadIdx.x] = len;
    __syncthreads();
    for (int off = 1; off < BLK; off <<= 1) {
        int t = ((int)threadIdx.x >= off) ? lds[threadIdx.x - off] : 0;
        __syncthreads();
        lds[threadIdx.x] += t;
        __syncthreads();
    }
    int incl = lds[threadIdx.x];
    if (threadIdx.x == BLK - 1) sbase = atomicAdd(cursor, incl);
    __syncthreads();
    if (!valid) return;
    int pos = sbase + incl - len;
    se[o] = make_int2(pos, pos + len);
    float acc = 0.f;
    for (int e = h; e >= 0;) {
        u64 nd = next2[e];
        unsigned pe = (unsigned)nd;
        acc += ent_w(pe);
        ent[pos++] = pe;
        e = (int)(nd >> 32);
    }
    if (o < Vb) nB[o] = acc;
    else nS[o - Vb] = acc;
}

// ---------------- composed 2-hop blur index build ----------------
// out = Bk(Bj in):  out[i] = in[i] + .5(in[a1]+in[a2]+in[A]+in[B])
//                          + .25(in[A1]+in[A2]+in[B1]+in[B2])
// A,B = bn_k[i]; a* = bn_j[i]; A* = bn_j[A]; B* = bn_j[B]; missing -> 0 and
// in[0]==0 keeps the algebra exact. Planes (stride V): a1 a2 A A1 A2 B B1 B2.
__global__ void k_compose(const int* __restrict__ bnb, int Mb, int Vb,
                          const int* __restrict__ bns, int Ms, int Vs,
                          int* __restrict__ cidxB, int* __restrict__ cidxS) {
    int t = blockIdx.x * BLK + threadIdx.x;
    int TB = 3 * Vb;
    const int* bnj; const int* bnk; int* c; int i, V;
    if (t < TB) {
        int p = t / Vb;
        i = t - p * Vb;
        if (i == 0) return;
        bnj = bnb + (size_t)(2 * p) * Mb * 2;
        bnk = bnb + (size_t)(2 * p + 1) * Mb * 2;
        c = cidxB + (size_t)p * 8 * Vb;
        V = Vb;
    } else {
        i = t - TB;
        if (i >= Vs || i == 0) return;
        bnj = bns;
        bnk = bns + (size_t)Ms * 2;
        c = cidxS;
        V = Vs;
    }
    int A = bnk[(size_t)(i - 1) * 2 + 0];
    int B = bnk[(size_t)(i - 1) * 2 + 1];
    int a1 = bnj[(size_t)(i - 1) * 2 + 0];
    int a2 = bnj[(size_t)(i - 1) * 2 + 1];
    int A1 = 0, A2 = 0, B1 = 0, B2 = 0;
    if (A > 0) { A1 = bnj[(size_t)(A - 1) * 2 + 0]; A2 = bnj[(size_t)(A - 1) * 2 + 1]; }
    if (B > 0) { B1 = bnj[(size_t)(B - 1) * 2 + 0]; B2 = bnj[(size_t)(B - 1) * 2 + 1]; }
    c[0 * (size_t)V + i] = a1;
    c[1 * (size_t)V + i] = a2;
    c[2 * (size_t)V + i] = A;
    c[3 * (size_t)V + i] = A1;
    c[4 * (size_t)V + i] = A2;
    c[5 * (size_t)V + i] = B;
    c[6 * (size_t)V + i] = B1;
    c[7 * (size_t)V + i] = B2;
}

// ---------------- fused 2-hop blur cores (fp32 tables) ----------------
__device__ __forceinline__ void blur2f4_core(const float4* __restrict__ in, float4* __restrict__ out,
                                             const int* __restrict__ c, int V, int i) {
    if (i == 0) { out[0] = f4zero(); return; }
    int a1 = c[0 * (size_t)V + i], a2 = c[1 * (size_t)V + i];
    int A  = c[2 * (size_t)V + i], A1 = c[3 * (size_t)V + i], A2 = c[4 * (size_t)V + i];
    int B  = c[5 * (size_t)V + i], B1 = c[6 * (size_t)V + i], B2 = c[7 * (size_t)V + i];
    float4 vi = in[i], va1 = in[a1], va2 = in[a2];
    float4 vA = in[A], vA1 = in[A1], vA2 = in[A2];
    float4 vB = in[B], vB1 = in[B1], vB2 = in[B2];
    float4 o;
    o.x = vi.x + 0.5f * (va1.x + va2.x + vA.x + vB.x) + 0.25f * (vA1.x + vA2.x + vB1.x + vB2.x);
    o.y = vi.y + 0.5f * (va1.y + va2.y + vA.y + vB.y) + 0.25f * (vA1.y + vA2.y + vB1.y + vB2.y);
    o.z = vi.z + 0.5f * (va1.z + va2.z + vA.z + vB.z) + 0.25f * (vA1.z + vA2.z + vB1.z + vB2.z);
    o.w = vi.w + 0.5f * (va1.w + va2.w + vA.w + vB.w) + 0.25f * (vA1.w + vA2.w + vB1.w + vB2.w);
    out[i] = o;
}

__device__ __forceinline__ void blur2f_core(const float* __restrict__ in, float* __restrict__ out,
                                            const int* __restrict__ c, int V, int i) {
    if (i == 0) { out[0] = 0.f; return; }
    int a1 = c[0 * (size_t)V + i], a2 = c[1 * (size_t)V + i];
    int A  = c[2 * (size_t)V + i], A1 = c[3 * (size_t)V + i], A2 = c[4 * (size_t)V + i];
    int B  = c[5 * (size_t)V + i], B1 = c[6 * (size_t)V + i], B2 = c[7 * (size_t)V + i];
    out[i] = in[i] + 0.5f * (in[a1] + in[a2] + in[A] + in[B])
                   + 0.25f * (in[A1] + in[A2] + in[B1] + in[B2]);
}

__device__ __forceinline__ void blur1f4_core(const float4* __restrict__ in, float4* __restrict__ out,
                                             const int* __restrict__ bn, int i) {
    if (i == 0) { out[0] = f4zero(); return; }
    int n1 = bn[(size_t)(i - 1) * 2 + 0];
    int n2 = bn[(size_t)(i - 1) * 2 + 1];
    float4 a = in[i], b = in[n1], c = in[n2];
    out[i] = make_float4(a.x + 0.5f * (b.x + c.x), a.y + 0.5f * (b.y + c.y),
                         a.z + 0.5f * (b.z + c.z), a.w + 0.5f * (b.w + c.w));
}

// fused-pair on both lattices (float4)
__global__ void k_blur2f4_both(const float4* __restrict__ inB, float4* __restrict__ outB,
                               const int* __restrict__ cB, int Vb,
                               const float4* __restrict__ inS, float4* __restrict__ outS,
                               const int* __restrict__ cS, int Vs) {
    int i = blockIdx.x * BLK + threadIdx.x;
    if (i < Vb) blur2f4_core(inB, outB, cB, Vb, i);
    else if (i - Vb < Vs) blur2f4_core(inS, outS, cS, Vs, i - Vb);
}
// fused-pair bilateral + single-hop spatial (float4)
__global__ void k_blur2f4_b1s(const float4* __restrict__ inB, float4* __restrict__ outB,
                              const int* __restrict__ cB, int Vb,
                              const float4* __restrict__ inS, float4* __restrict__ outS,
                              const int* __restrict__ bnS, int Vs) {
    int i = blockIdx.x * BLK + threadIdx.x;
    if (i < Vb) blur2f4_core(inB, outB, cB, Vb, i);
    else if (i - Vb < Vs) blur1f4_core(inS, outS, bnS, i - Vb);
}
// fused-pair bilateral only (float4)
__global__ void k_blur2f4_b(const float4* __restrict__ inB, float4* __restrict__ outB,
                            const int* __restrict__ cB, int Vb) {
    int i = blockIdx.x * BLK + threadIdx.x;
    if (i < Vb) blur2f4_core(inB, outB, cB, Vb, i);
}
// fp32 scalar variants for the normalizer chain
__global__ void k_blur2f_both(const float* __restrict__ inB, float* __restrict__ outB,
                              const int* __restrict__ cB, int Vb,
                              const float* __restrict__ inS, float* __restrict__ outS,
                              const int* __restrict__ cS, int Vs) {
    int i = blockIdx.x * BLK + threadIdx.x;
    if (i < Vb) blur2f_core(inB, outB, cB, Vb, i);
    else if (i - Vb < Vs) blur2f_core(inS, outS, cS, Vs, i - Vb);
}
__global__ void k_blur2f_b1s(const float* __restrict__ inB, float* __restrict__ outB,
                             const int* __restrict__ cB, int Vb,
                             const float* __restrict__ inS, float* __restrict__ outS,
                             const int* __restrict__ bnS, int Vs) {
    int i = blockIdx.x * BLK + threadIdx.x;
    if (i < Vb) blur2f_core(inB, outB, cB, Vb, i);
    else if (i - Vb < Vs) {
        int idx = i - Vb;
        if (idx == 0) { outS[0] = 0.f; return; }
        int n1 = bnS[(size_t)(idx - 1) * 2 + 0];
        int n2 = bnS[(size_t)(idx - 1) * 2 + 1];
        outS[idx] = inS[idx] + 0.5f * (inS[n1] + inS[n2]);
    }
}
__global__ void k_blur2f_b(const float* __restrict__ inB, float* __restrict__ outB,
                           const int* __restrict__ cB, int Vb) {
    int i = blockIdx.x * BLK + threadIdx.x;
    if (i < Vb) blur2f_core(inB, outB, cB, Vb, i);
}

// ---------------- gather-based splat: solo bilateral + 4-lane-cooperative spatial ----
// Bilateral vertices (avg ~4 entries) get one thread each; spatial vertices
// (avg ~26 entries) get an ALIGNED group of 4 lanes with shfl_xor reduce, fixing
// the serial-chain tail. Vb4 = Vb rounded up to 4 keeps groups lane-aligned
// (4-aligned groups never straddle wave or block boundaries).
__global__ void k_gather4f_both(const unsigned* __restrict__ ent, const int2* __restrict__ se,
                                int Vb, int Vb4, int Vs,
                                float4* __restrict__ tB, float4* __restrict__ tS,
                                const float4* __restrict__ Q) {
    int i = blockIdx.x * BLK + threadIdx.x;
    if (i < Vb) {
        int2 r = se[i];
        float ax = 0.f, ay = 0.f, az = 0.f, aw = 0.f;
        for (int k = r.x; k < r.y; k++) {
            unsigned en = ent[k];
            float w = ent_w(en);
            float4 q = Q[ent_pix(en)];
            ax += w * q.x; ay += w * q.y; az += w * q.z; aw += w * q.w;
        }
        tB[i] = make_float4(ax, ay, az, aw);
        return;
    }
    if (i < Vb4) return;                 // alignment gap
    int j = i - Vb4;
    int v = j >> 2;                      // spatial vertex index
    if (v >= Vs) return;
    int sub = j & 3;
    int2 r = se[Vb + v];
    float ax = 0.f, ay = 0.f, az = 0.f, aw = 0.f;
    for (int k = r.x + sub; k < r.y; k += 4) {
        unsigned en = ent[k];
        float w = ent_w(en);
        float4 q = Q[ent_pix(en)];
        ax += w * q.x; ay += w * q.y; az += w * q.z; aw += w * q.w;
    }
    // reduce across the aligned 4-lane group
    ax += __shfl_xor(ax, 1); ay += __shfl_xor(ay, 1);
    az += __shfl_xor(az, 1); aw += __shfl_xor(aw, 1);
    ax += __shfl_xor(ax, 2); ay += __shfl_xor(ay, 2);
    az += __shfl_xor(az, 2); aw += __shfl_xor(aw, 2);
    if (sub == 0) tS[v] = make_float4(ax, ay, az, aw);
}

// ---------------- plain 1-hop blurs (unfused tier + fallback) ----------------
__global__ void k_blur1(const float* __restrict__ in, float* __restrict__ out,
                        const int* __restrict__ bn, int M) {
    int i = blockIdx.x * BLK + threadIdx.x;
    if (i > M) return;
    if (i == 0) { out[0] = 0.f; return; }
    int n1 = bn[(size_t)(i - 1) * 2 + 0];
    int n2 = bn[(size_t)(i - 1) * 2 + 1];
    out[i] = in[i] + 0.5f * (in[n1] + in[n2]);
}

__global__ void k_blur1_both(const float* __restrict__ inB, float* __restrict__ outB,
                             const int* __restrict__ bnB, int Mb,
                             const float* __restrict__ inS, float* __restrict__ outS,
                             const int* __restrict__ bnS, int Ms) {
    int i = blockIdx.x * BLK + threadIdx.x;
    const float* in; float* out; const int* bn; int M, idx;
    if (i <= Mb) { in = inB; out = outB; bn = bnB; M = Mb; idx = i; }
    else {
        idx = i - (Mb + 1);
        if (idx > Ms) return;
        in = inS; out = outS; bn = bnS; M = Ms;
    }
    if (idx == 0) { out[0] = 0.f; return; }
    int n1 = bn[(size_t)(idx - 1) * 2 + 0];
    int n2 = bn[(size_t)(idx - 1) * 2 + 1];
    out[idx] = in[idx] + 0.5f * (in[n1] + in[n2]);
}

__global__ void k_blur4(const float4* __restrict__ in, float4* __restrict__ out,
                        const int* __restrict__ bn, int M) {
    int i = blockIdx.x * BLK + threadIdx.x;
    if (i > M) return;
    blur1f4_core(in, out, bn, i);
}

__global__ void k_blur4_both(const float4* __restrict__ inB, float4* __restrict__ outB,
                             const int* __restrict__ bnB, int Mb,
                             const float4* __restrict__ inS, float4* __restrict__ outS,
                             const int* __restrict__ bnS, int Ms) {
    int i = blockIdx.x * BLK + threadIdx.x;
    if (i <= Mb) blur1f4_core(inB, outB, bnB, i);
    else if (i - (Mb + 1) <= Ms) blur1f4_core(inS, outS, bnS, i - (Mb + 1));
}

// ---------------- normalizer slice + prescale -> packed (weight,idx) ----------------
__global__ void k_norm_prescale(const float* __restrict__ nTb, const float* __restrict__ wsb,
                                const int* __restrict__ osb,
                                const float* __restrict__ nTs, const float* __restrict__ wss,
                                const int* __restrict__ oss,
                                int2* __restrict__ pwb, int2* __restrict__ pws) {
    int n = blockIdx.x * BLK + threadIdx.x;
    if (n >= NPIX) return;
    float sb = 0.f;
#pragma unroll
    for (int r = 0; r < 6; r++) sb += wsb[n * 6 + r] * nTb[osb[n * 6 + r]];
    float cb = BI_COMPAT * ALPHA_B / (ALPHA_B * sb + 1e-20f);
#pragma unroll
    for (int r = 0; r < 6; r++)
        pwb[n * 6 + r] = make_int2(__float_as_int(wsb[n * 6 + r] * cb), osb[n * 6 + r]);
    float ss = 0.f;
#pragma unroll
    for (int r = 0; r < 3; r++) ss += wss[n * 3 + r] * nTs[oss[n * 3 + r]];
    float cs = SP_COMPAT * ALPHA_S / (ALPHA_S * ss + 1e-20f);
#pragma unroll
    for (int r = 0; r < 3; r++)
        pws[n * 3 + r] = make_int2(__float_as_int(wss[n * 3 + r] * cs), oss[n * 3 + r]);
}

// ---------------- fused slice + message + softmax (packed weights) ----------------
__global__ void k_slice_combine_f(const float4* __restrict__ u,
                                  const float4* __restrict__ tb, const int2* __restrict__ pwb,
                                  const float4* __restrict__ ts, const int2* __restrict__ pws,
                                  float4* __restrict__ Qout) {
    int n = blockIdx.x * BLK + threadIdx.x;
    if (n >= NPIX) return;
    float4 uu = u[n];
    float l0 = -uu.x, l1 = -uu.y, l2 = -uu.z, l3 = -uu.w;
#pragma unroll
    for (int r = 0; r < 6; r++) {
        int2 p = pwb[n * 6 + r];
        float w = __int_as_float(p.x);
        float4 t = tb[p.y];
        l0 += w * t.x; l1 += w * t.y; l2 += w * t.z; l3 += w * t.w;
    }
#pragma unroll
    for (int r = 0; r < 3; r++) {
        int2 p = pws[n * 3 + r];
        float w = __int_as_float(p.x);
        float4 t = ts[p.y];
        l0 += w * t.x; l1 += w * t.y; l2 += w * t.z; l3 += w * t.w;
    }
    float m = fmaxf(fmaxf(l0, l1), fmaxf(l2, l3));
    float e0 = expf(l0 - m), e1 = expf(l1 - m), e2 = expf(l2 - m), e3 = expf(l3 - m);
    float inv = 1.0f / (e0 + e1 + e2 + e3);
    Qout[n] = make_float4(e0 * inv, e1 * inv, e2 * inv, e3 * inv);
}

// ---------------- fallback (fp32 atomic splat path) ----------------
template <int D1>
__global__ void k_splat1(const float* __restrict__ ws, const int* __restrict__ os,
                         float* __restrict__ table) {
    int n = blockIdx.x * BLK + threadIdx.x;
    if (n >= NPIX) return;
#pragma unroll
    for (int r = 0; r < D1; r++) atomicAdd(&table[os[n * D1 + r]], ws[n * D1 + r]);
}

template <int D1>
__global__ void k_splat4(const float4* __restrict__ Q, const float* __restrict__ ws,
                         const int* __restrict__ os, float* __restrict__ table) {
    int n = blockIdx.x * BLK + threadIdx.x;
    if (n >= NPIX) return;
    float4 q = Q[n];
#pragma unroll
    for (int r = 0; r < D1; r++) {
        float w = ws[n * D1 + r];
        int o = os[n * D1 + r];
        float* t = table + 4 * (size_t)o;
        atomicAdd(t + 0, q.x * w);
        atomicAdd(t + 1, q.y * w);
        atomicAdd(t + 2, q.z * w);
        atomicAdd(t + 3, q.w * w);
    }
}

template <int D1>
__global__ void k_norm_slice(const float* __restrict__ table, const float* __restrict__ ws,
                             const int* __restrict__ os, float alpha,
                             float* __restrict__ inv_out) {
    int n = blockIdx.x * BLK + threadIdx.x;
    if (n >= NPIX) return;
    float s = 0.f;
#pragma unroll
    for (int r = 0; r < D1; r++) s += ws[n * D1 + r] * table[os[n * D1 + r]];
    inv_out[n] = 1.0f / (alpha * s + 1e-20f);
}

__global__ void k_slice_combine(const float4* __restrict__ u,
                                const float4* __restrict__ tb, const float* __restrict__ wsb,
                                const int* __restrict__ osb,
                                const float4* __restrict__ ts, const float* __restrict__ wss,
                                const int* __restrict__ oss,
                                const float* __restrict__ inv_nb,
                                const float* __restrict__ inv_ns,
                                float4* __restrict__ Qout) {
    int n = blockIdx.x * BLK + threadIdx.x;
    if (n >= NPIX) return;
    float4 ab = f4zero();
#pragma unroll
    for (int r = 0; r < 6; r++) {
        float w = wsb[n * 6 + r];
        float4 t = tb[osb[n * 6 + r]];
        ab.x += w * t.x; ab.y += w * t.y; ab.z += w * t.z; ab.w += w * t.w;
    }
    float4 as = f4zero();
#pragma unroll
    for (int r = 0; r < 3; r++) {
        float w = wss[n * 3 + r];
        float4 t = ts[oss[n * 3 + r]];
        as.x += w * t.x; as.y += w * t.y; as.z += w * t.z; as.w += w * t.w;
    }
    float cb = BI_COMPAT * ALPHA_B * inv_nb[n];
    float cs = SP_COMPAT * ALPHA_S * inv_ns[n];
    float4 uu = u[n];
    float l0 = -uu.x + cb * ab.x + cs * as.x;
    float l1 = -uu.y + cb * ab.y + cs * as.y;
    float l2 = -uu.z + cb * ab.z + cs * as.z;
    float l3 = -uu.w + cb * ab.w + cs * as.w;
    float m = fmaxf(fmaxf(l0, l1), fmaxf(l2, l3));
    float e0 = expf(l0 - m), e1 = expf(l1 - m), e2 = expf(l2 - m), e3 = expf(l3 - m);
    float inv = 1.0f / (e0 + e1 + e2 + e3);
    Qout[n] = make_float4(e0 * inv, e1 * inv, e2 * inv, e3 * inv);
}

extern "C" void kernel_launch(void* const* d_in, const int* in_sizes, int n_in,
                              void* d_out, int out_size, void* d_ws, size_t ws_size,
                              hipStream_t stream) {
    const float* unary = (const float*)d_in[0];
    const float* wsb   = (const float*)d_in[1];
    const int*   osb   = (const int*)d_in[2];
    const int*   bnb   = (const int*)d_in[3];
    const float* wss   = (const float*)d_in[5];
    const int*   oss   = (const int*)d_in[6];
    const int*   bns   = (const int*)d_in[7];
    const int Mb = in_sizes[3] / 12;   // bn_b is (6, Mb, 2)
    const int Ms = in_sizes[7] / 6;    // bn_s is (3, Ms, 2)
    const int Vb = Mb + 1, Vs = Ms + 1;
    const int V = Vb + Vs;
    const int Vb4 = (Vb + 3) & ~3;     // aligned base for 4-lane spatial groups

    float* Q = (float*)d_out;  // N x 4, final value IS the output

    char* p = (char*)d_ws;
    auto alloc = [&](size_t nbytes) -> void* {
        void* r = (void*)p;
        p += (nbytes + 15) & ~(size_t)15;
        return r;
    };
    // ---- aliasable region: pwb+pws = TOTE*8 bytes exactly; the 8B next2 node
    // array aliases it (next2 dead after k_compact2; pwb/pws first written by
    // k_norm_prescale, which runs after). Tables/nB* also live here (first
    // written after compaction).
    char* region0 = p;
    int2* pwb = (int2*)alloc((size_t)TOTB * 8);
    int2* pws = (int2*)alloc((size_t)TOTS * 8);
    float4* tAb = (float4*)alloc((size_t)Vb * 16);
    float4* tBb = (float4*)alloc((size_t)Vb * 16);
    float4* tAs = (float4*)alloc((size_t)Vs * 16);
    float4* tBs = (float4*)alloc((size_t)Vs * 16);
    float* nBb = (float*)alloc((size_t)Vb * 4);
    float* nBs = (float*)alloc((size_t)Vs * 4);
    u64*  next2 = (u64*)region0;       // aliases pwb+pws exactly (TOTE*8 bytes)
    // ---- non-aliased (live across build) ----
    float* nAb = (float*)alloc((size_t)Vb * 4);
    float* nAs = (float*)alloc((size_t)Vs * 4);
    int2* se   = (int2*)alloc((size_t)V * 8);
    int*  head = (int*)alloc((size_t)V * 4);
    unsigned* ent = (unsigned*)alloc((size_t)TOTE * 4);
    int*  cursor = (int*)alloc(16);
    size_t base_need = (size_t)(p - (char*)d_ws);
    // composed 2-hop indices: bilateral 3 pairs x 8 planes x Vb, spatial 1 x 8 x Vs
    int* cidxB = (int*)alloc((size_t)Vb * 8 * 3 * 4);
    int* cidxS = (int*)alloc((size_t)Vs * 8 * 4);
    size_t need_fused = (size_t)(p - (char*)d_ws);
    bool use_gather = base_need <= ws_size;
    bool use_fused = need_fused <= ws_size;

    dim3 blk(BLK);
    dim3 gN((NPIX + BLK - 1) / BLK);
    dim3 gVb((Vb + BLK - 1) / BLK);
    dim3 gV((V + BLK - 1) / BLK);
    dim3 gG((Vb4 + 4 * Vs + BLK - 1) / BLK);     // gather grid (coop spatial)
    dim3 gVBS((Vb + Vs + BLK - 1) / BLK);
    dim3 gC((3 * Vb + Vs + BLK - 1) / BLK);

    if (use_gather) {
        // ---- build CSR via linked-list inversion + compaction ----
        hipMemsetAsync(head, 0xFF, (size_t)V * 4, stream);  // -1 sentinel
        hipMemsetAsync(cursor, 0, 16, stream);
        if (use_fused)
            k_compose<<<gC, blk, 0, stream>>>(bnb, Mb, Vb, bns, Ms, Vs, cidxB, cidxS);
        k_link2_softmax<<<gN, blk, 0, stream>>>(osb, wsb, oss, wss, head, next2,
                                                (const float4*)unary, (float4*)Q, Vb);
        k_compact2<<<gV, blk, 0, stream>>>(head, next2, ent, se, nAb, nAs, cursor, V, Vb);

        const int* cB01 = cidxB;
        const int* cB23 = cidxB + (size_t)1 * 8 * Vb;
        const int* cB45 = cidxB + (size_t)2 * 8 * Vb;
        const int* bnS2 = bns + (size_t)2 * Ms * 2;

        // ---- normalizer chain + prescale ----
        if (use_fused) {
            k_blur2f_both<<<gVBS, blk, 0, stream>>>(nAb, nBb, cB01, Vb, nAs, nBs, cidxS, Vs);
            k_blur2f_b1s<<<gVBS, blk, 0, stream>>>(nBb, nAb, cB23, Vb, nBs, nAs, bnS2, Vs);
            k_blur2f_b<<<gVb, blk, 0, stream>>>(nAb, nBb, cB45, Vb);
            k_norm_prescale<<<gN, blk, 0, stream>>>(nBb, wsb, osb, nAs, wss, oss, pwb, pws);
        } else {
            float* a = nAb; float* b = nBb;
            float* as_ = nAs; float* bs_ = nBs;
            for (int j = 0; j < 3; j++) {
                k_blur1_both<<<gVBS, blk, 0, stream>>>(a, b, bnb + (size_t)j * Mb * 2, Mb,
                                                       as_, bs_, bns + (size_t)j * Ms * 2, Ms);
                float* t = a; a = b; b = t;
                t = as_; as_ = bs_; bs_ = t;
            }
            for (int j = 3; j < 6; j++) {
                k_blur1<<<gVb, blk, 0, stream>>>(a, b, bnb + (size_t)j * Mb * 2, Mb);
                float* t = a; a = b; b = t;
            }
            k_norm_prescale<<<gN, blk, 0, stream>>>(a, wsb, osb, as_, wss, oss, pwb, pws);
        }

        // ---- 10 mean-field iterations ----
        for (int it = 0; it < 10; it++) {
            k_gather4f_both<<<gG, blk, 0, stream>>>(ent, se, Vb, Vb4, Vs, tAb, tAs,
                                                    (const float4*)Q);
            if (use_fused) {
                // bil: tAb -(01)-> tBb -(23)-> tAb -(45)-> tBb ; sp: tAs -(01)-> tBs -(2)-> tAs
                k_blur2f4_both<<<gVBS, blk, 0, stream>>>(tAb, tBb, cB01, Vb, tAs, tBs, cidxS, Vs);
                k_blur2f4_b1s<<<gVBS, blk, 0, stream>>>(tBb, tAb, cB23, Vb, tBs, tAs, bnS2, Vs);
                k_blur2f4_b<<<gVb, blk, 0, stream>>>(tAb, tBb, cB45, Vb);
                k_slice_combine_f<<<gN, blk, 0, stream>>>((const float4*)unary,
                                                          tBb, pwb, tAs, pws, (float4*)Q);
            } else {
                float4* a = tAb; float4* b = tBb;
                float4* as_ = tAs; float4* bs_ = tBs;
                for (int j = 0; j < 3; j++) {
                    k_blur4_both<<<gVBS, blk, 0, stream>>>(a, b, bnb + (size_t)j * Mb * 2, Mb,
                                                           as_, bs_, bns + (size_t)j * Ms * 2, Ms);
                    float4* t = a; a = b; b = t;
                    t = as_; as_ = bs_; bs_ = t;
                }
                for (int j = 3; j < 6; j++) {
                    k_blur4<<<gVb, blk, 0, stream>>>(a, b, bnb + (size_t)j * Mb * 2, Mb);
                    float4* t = a; a = b; b = t;
                }
                k_slice_combine_f<<<gN, blk, 0, stream>>>((const float4*)unary,
                                                          a, pwb, as_, pws, (float4*)Q);
            }
        }
    } else {
        // ---- fallback: fp32 atomic splat path ----
        char* q = (char*)d_ws;
        auto alloc2 = [&](size_t nbytes) -> void* {
            void* r = (void*)q;
            q += (nbytes + 15) & ~(size_t)15;
            return r;
        };
        float* fAb = (float*)alloc2((size_t)Vb * 4 * sizeof(float));
        float* fBb = (float*)alloc2((size_t)Vb * 4 * sizeof(float));
        float* fAs = (float*)alloc2((size_t)Vs * 4 * sizeof(float));
        float* fBs = (float*)alloc2((size_t)Vs * 4 * sizeof(float));
        float* inv_nb = (float*)alloc2(NPIX * sizeof(float));
        float* inv_ns = (float*)alloc2(NPIX * sizeof(float));
        dim3 gMb((Mb + 1 + BLK - 1) / BLK);
        dim3 gMs((Ms + 1 + BLK - 1) / BLK);

        hipMemsetAsync(fAb, 0, (size_t)Vb * sizeof(float), stream);
        k_splat1<6><<<gN, blk, 0, stream>>>(wsb, osb, fAb);
        {
            float* a = fAb; float* b = fBb;
            for (int j = 0; j < 6; j++) {
                k_blur1<<<gMb, blk, 0, stream>>>(a, b, bnb + (size_t)j * Mb * 2, Mb);
                float* t = a; a = b; b = t;
            }
            k_norm_slice<6><<<gN, blk, 0, stream>>>(a, wsb, osb, ALPHA_B, inv_nb);
        }
        hipMemsetAsync(fAs, 0, (size_t)Vs * sizeof(float), stream);
        k_splat1<3><<<gN, blk, 0, stream>>>(wss, oss, fAs);
        {
            float* a = fAs; float* b = fBs;
            for (int j = 0; j < 3; j++) {
                k_blur1<<<gMs, blk, 0, stream>>>(a, b, bns + (size_t)j * Ms * 2, Ms);
                float* t = a; a = b; b = t;
            }
            k_norm_slice<3><<<gN, blk, 0, stream>>>(a, wss, oss, ALPHA_S, inv_ns);
        }
        k_softmax_init<<<gN, blk, 0, stream>>>((const float4*)unary, (float4*)Q);
        for (int it = 0; it < 10; it++) {
            hipMemsetAsync(fAb, 0, (size_t)Vb * 4 * sizeof(float), stream);
            k_splat4<6><<<gN, blk, 0, stream>>>((const float4*)Q, wsb, osb, fAb);
            float* a = fAb; float* b = fBb;
            for (int j = 0; j < 6; j++) {
                k_blur4<<<gMb, blk, 0, stream>>>((const float4*)a, (float4*)b,
                                                 bnb + (size_t)j * Mb * 2, Mb);
                float* t = a; a = b; b = t;
            }
            float* finb = a;
            hipMemsetAsync(fAs, 0, (size_t)Vs * 4 * sizeof(float), stream);
            k_splat4<3><<<gN, blk, 0, stream>>>((const float4*)Q, wss, oss, fAs);
            float* as_ = fAs; float* bs_ = fBs;
            for (int j = 0; j < 3; j++) {
                k_blur4<<<gMs, blk, 0, stream>>>((const float4*)as_, (float4*)bs_,
                                                 bns + (size_t)j * Ms * 2, Ms);
                float* t = as_; as_ = bs_; bs_ = t;
            }
            float* fins = as_;
            k_slice_combine<<<gN, blk, 0, stream>>>((const float4*)unary,
                                                    (const float4*)finb, wsb, osb,
                                                    (const float4*)fins, wss, oss,
                                                    inv_nb, inv_ns, (float4*)Q);
        }
    }
}